// Round 13
// baseline (48.143 us; speedup 1.0000x reference)
//
#include <hip/hip_runtime.h>

#define C_CH 64
#define NX 432
#define NY 496
#define NYQ 124                    // NY/4
#define PLANEQ (NX * NYQ)          // float4s per (b,c) plane = 53568
#define SLOTS 64                   // staged pillars/column (mean 27.8; >64 handled by slow path)
#define CAP 512                    // colist capacity (>= NY=496: unique coords can't exceed)

// ---------- fast path: tiny memset + compact-list scatter + LDS-staged writer ----------

// Append pillar (local j, y) into its output column's compact list.
// col = s*NX + (NX-1-x)  (flip pre-applied). Pack (j<<9)|y: j<12000<2^14, y<496<2^9.
__global__ void scatter_idx_kernel(const int* __restrict__ bidx,
                                   const int* __restrict__ sidx,
                                   int* __restrict__ colcnt,
                                   int* __restrict__ colist,
                                   int M, int mper) {
    int m = blockIdx.x * blockDim.x + threadIdx.x;
    if (m >= M) return;
    int y = bidx[3 * m + 1];
    int x = bidx[3 * m + 2];
    int s = sidx[m];
    int j = m - s * mper;
    int col = s * NX + (NX - 1 - x);
    int slot = atomicAdd(&colcnt[col], 1);
    if (slot < CAP) colist[col * CAP + slot] = (j << 9) | y;
}

// One block per (b, xo) column. ~19 KB LDS -> 8 blocks/CU (thread cap).
// Phase A: read count + <=cnt packed entries (one coalesced burst), build LDS
//   row map (SLOTS = dummy zero row for empty sites).
// Phase B: coalesced fetch of staged pillar rows (256 B each) into LDS.
// Phase C: branchless fast path — every quad is 4 LDS reads + 1 coalesced
//   float4 store (128-thread group per c-plane row, 1984 B contiguous).
__global__ __launch_bounds__(256) void column_write_kernel(
        const float* __restrict__ feats,
        const int* __restrict__ colcnt,
        const int* __restrict__ colist,
        float4* __restrict__ out, int mper) {
    __shared__ int4  map4[NYQ];              // slot in [0,SLOTS], or <=-2 -> direct gather
    __shared__ int   slot_m[SLOTS];          // global pillar index m
    __shared__ float rows[SLOTS + 1][C_CH + 1]; // +1 pad: bank = (s + c) % 32
    int* map_row = (int*)map4;

    const int col = blockIdx.x;              // b*NX + xo
    const int b   = col / NX;
    const int xo  = col - b * NX;
    const int tid = threadIdx.x;
    const int mbase = b * mper;

    // Phase A
    const int cnt = colcnt[col];             // uniform scalar load (broadcast)
    for (int i = tid; i < NY; i += 256) map_row[i] = SLOTS;
    if (tid < C_CH) rows[SLOTS][tid] = 0.0f; // dummy zero row
    __syncthreads();                         // map_row init done before scatter-writes
    const int* cl = colist + (size_t)col * CAP;
    for (int e = tid; e < cnt; e += 256) {   // usually one iter (cnt ~28)
        int v = cl[e];
        int y = v & 511;
        int j = v >> 9;
        if (e < SLOTS) { slot_m[e] = mbase + j; map_row[y] = e; }
        else map_row[y] = -2 - j;            // overflow: direct gather in phase C
    }
    __syncthreads();

    // Phase B
    const int n = (cnt < SLOTS) ? cnt : SLOTS;
    for (int e = tid; e < n * C_CH; e += 256) {
        int s = e >> 6;
        int c = e & (C_CH - 1);
        rows[s][c] = feats[(size_t)slot_m[s] * C_CH + c];
    }
    __syncthreads();

    // Phase C
    const int t   = tid & 127;               // yq
    const int cof = tid >> 7;                // 0/1
    int4 mm = make_int4(SLOTS, SLOTS, SLOTS, SLOTS);
    if (t < NYQ) mm = map4[t];
    float4* ob = out + ((size_t)b * C_CH * NX + xo) * NYQ + t;

    if (cnt <= SLOTS) {                      // block-uniform: the always-taken path
        #pragma unroll 8
        for (int c2 = 0; c2 < C_CH / 2; ++c2) {
            int c = (c2 << 1) + cof;
            if (t < NYQ) {
                float4 v;
                v.x = rows[mm.x][c];
                v.y = rows[mm.y][c];
                v.z = rows[mm.z][c];
                v.w = rows[mm.w][c];
                ob[(size_t)c * PLANEQ] = v;
            }
        }
    } else {                                 // correct slow path (never in practice)
        for (int c2 = 0; c2 < C_CH / 2; ++c2) {
            int c = (c2 << 1) + cof;
            if (t < NYQ) {
                float4 v;
                v.x = (mm.x >= 0) ? rows[mm.x][c] : feats[(size_t)(mbase + (-2 - mm.x)) * C_CH + c];
                v.y = (mm.y >= 0) ? rows[mm.y][c] : feats[(size_t)(mbase + (-2 - mm.y)) * C_CH + c];
                v.z = (mm.z >= 0) ? rows[mm.z][c] : feats[(size_t)(mbase + (-2 - mm.z)) * C_CH + c];
                v.w = (mm.w >= 0) ? rows[mm.w][c] : feats[(size_t)(mbase + (-2 - mm.w)) * C_CH + c];
                ob[(size_t)c * PLANEQ] = v;
            }
        }
    }
}

// ---------- fallback path (if d_ws too small): zero + direct scatter ----------

__global__ void zero_out_kernel(float4* __restrict__ out, int nq) {
    int i = blockIdx.x * blockDim.x + threadIdx.x;
    if (i < nq) out[i] = make_float4(0.f, 0.f, 0.f, 0.f);
}

__global__ void scatter_feats_kernel(const float* __restrict__ feats,
                                     const int* __restrict__ bidx,
                                     const int* __restrict__ sidx,
                                     float* __restrict__ out, int M) {
    int tid = blockIdx.x * blockDim.x + threadIdx.x;
    if (tid >= M * C_CH) return;
    int m = tid >> 6;
    int c = tid & (C_CH - 1);
    int y = bidx[3 * m + 1];
    int x = bidx[3 * m + 2];
    int s = sidx[m];
    size_t o = (((size_t)s * C_CH + c) * NX + (NX - 1 - x)) * NY + y;
    out[o] = feats[tid];
}

extern "C" void kernel_launch(void* const* d_in, const int* in_sizes, int n_in,
                              void* d_out, int out_size, void* d_ws, size_t ws_size,
                              hipStream_t stream) {
    const float* feats = (const float*)d_in[0];
    const int*   bidx  = (const int*)d_in[1];
    const int*   sidx  = (const int*)d_in[2];
    float*       out   = (float*)d_out;

    const int M = in_sizes[0] / C_CH;               // 48000 pillars total
    const int B = out_size / (C_CH * NX * NY);      // 4
    const int mper = M / B;                         // 12000 (sample-contiguous)
    const int ncol = B * NX;                        // 1728 columns

    const size_t cnt_bytes = (size_t)ncol * sizeof(int);            // 6.9 KB
    const size_t ws_need   = cnt_bytes + (size_t)ncol * CAP * sizeof(int); // ~3.5 MB

    if (ws_size >= ws_need && mper < (1 << 14)) {
        int* colcnt = (int*)d_ws;
        int* colist = colcnt + ncol;
        hipMemsetAsync(colcnt, 0, cnt_bytes, stream);   // tiny (6.9 KB)
        scatter_idx_kernel<<<(M + 255) / 256, 256, 0, stream>>>(
            bidx, sidx, colcnt, colist, M, mper);
        column_write_kernel<<<ncol, 256, 0, stream>>>(
            feats, colcnt, colist, (float4*)out, mper);
    } else {
        int nq = out_size / 4;
        zero_out_kernel<<<(nq + 255) / 256, 256, 0, stream>>>((float4*)out, nq);
        int nt = M * C_CH;
        scatter_feats_kernel<<<(nt + 255) / 256, 256, 0, stream>>>(
            feats, bidx, sidx, out, M);
    }
}

// Round 14
// 45.059 us; speedup vs baseline: 1.0685x; 1.0685x over previous
//
#include <hip/hip_runtime.h>

#define C_CH 64
#define NX 432
#define NY 496
#define NYQ 124                    // NY/4
#define PLANEQ (NX * NYQ)          // float4s per (b,c) plane = 53568
#define SLOTS 64                   // staged pillars/column (mean 27.8; >64 handled by slow path)
#define NXCD 8
#define EMPTY16 0xFFFFu

// ---------- fast path: memset(-1) + uint16 index scatter + LDS-staged writer ----------

// Scatter global pillar index m (< 0xFFFF, launcher-guarded) into
// map[s, NX-1-x, y] as uint16 (flip pre-applied). Unique coords -> no races,
// no atomics.
__global__ void scatter_idx_kernel(const int* __restrict__ bidx,
                                   const int* __restrict__ sidx,
                                   unsigned short* __restrict__ map, int M) {
    int m = blockIdx.x * blockDim.x + threadIdx.x;
    if (m >= M) return;
    int y = bidx[3 * m + 1];
    int x = bidx[3 * m + 2];
    int s = sidx[m];
    map[(size_t)s * (NX * NY) + (size_t)(NX - 1 - x) * NY + y] = (unsigned short)m;
}

// One block per (b, xo) column, XCD-swizzled. ~19 KB LDS -> 8 blocks/CU, so
// each block's serial A->B prologue hides under 7 neighbors' store streams.
// Phase C fast path is BRANCHLESS: empty sites point at a dummy zero row, so
// every quad is 4 unconditional LDS reads + 1 coalesced float4 store.
__global__ __launch_bounds__(256) void column_write_kernel(
        const float* __restrict__ feats,
        const unsigned short* __restrict__ map,
        float4* __restrict__ out, int nwg) {
    __shared__ int4  map4[NYQ];              // slot in [0,SLOTS] (SLOTS = zero row), <=-2 direct
    __shared__ int   slot_m[SLOTS];
    __shared__ float rows[SLOTS + 1][C_CH + 1]; // +1 pad: bank = (s + c) % 32
    __shared__ int   cnt, ovf;

    int* map_row = (int*)map4;
    const int chunk = nwg / NXCD;            // bijective: launcher guarantees nwg % 8 == 0
    const int blk = (blockIdx.x % NXCD) * chunk + blockIdx.x / NXCD;
    const int b   = blk / NX;
    const int xo  = blk - b * NX;
    const int tid = threadIdx.x;

    if (tid == 0) { cnt = 0; ovf = 0; }
    if (tid < C_CH) rows[SLOTS][tid] = 0.0f; // dummy zero row for empty sites
    __syncthreads();

    // Phase A: read column map slice (992 B contiguous ushorts), compact into slots
    const unsigned short* mp = map + ((size_t)b * NX + xo) * NY;
    for (int y = tid; y < NY; y += 256) {
        unsigned int m = mp[y];
        int v = SLOTS;                       // empty -> zero row
        if (m != EMPTY16) {
            int s = atomicAdd(&cnt, 1);
            if (s < SLOTS) { slot_m[s] = (int)m; v = s; }
            else { v = -2 - (int)m; ovf = 1; } // overflow: direct gather in phase C
        }
        map_row[y] = v;
    }
    __syncthreads();

    // Phase B: coalesced fetch of occupied pillar rows (256 B each) into LDS
    const int n = (cnt < SLOTS) ? cnt : SLOTS;
    for (int e = tid; e < n * C_CH; e += 256) {
        int s = e >> 6;
        int c = e & (C_CH - 1);
        rows[s][c] = feats[(size_t)slot_m[s] * C_CH + c];
    }
    __syncthreads();

    // Phase C: stream the (C=64, NYQ=124) slice. 128-thread group per c-plane
    // row -> 124 consecutive float4 stores (1984 B contiguous). All loads LDS.
    const int t    = tid & 127;              // yq
    const int cof  = tid >> 7;               // 0/1
    int4 mm = make_int4(SLOTS, SLOTS, SLOTS, SLOTS);
    if (t < NYQ) mm = map4[t];
    float4* ob = out + ((size_t)b * C_CH * NX + xo) * NYQ + t;

    if (!ovf) {                              // block-uniform: the always-taken path
        #pragma unroll 8
        for (int c2 = 0; c2 < C_CH / 2; ++c2) {
            int c = (c2 << 1) + cof;
            if (t < NYQ) {
                float4 v;
                v.x = rows[mm.x][c];
                v.y = rows[mm.y][c];
                v.z = rows[mm.z][c];
                v.w = rows[mm.w][c];
                ob[(size_t)c * PLANEQ] = v;
            }
        }
    } else {                                 // correct slow path (never in practice)
        for (int c2 = 0; c2 < C_CH / 2; ++c2) {
            int c = (c2 << 1) + cof;
            if (t < NYQ) {
                float4 v;
                v.x = (mm.x >= 0) ? rows[mm.x][c] : feats[(size_t)(-2 - mm.x) * C_CH + c];
                v.y = (mm.y >= 0) ? rows[mm.y][c] : feats[(size_t)(-2 - mm.y) * C_CH + c];
                v.z = (mm.z >= 0) ? rows[mm.z][c] : feats[(size_t)(-2 - mm.z) * C_CH + c];
                v.w = (mm.w >= 0) ? rows[mm.w][c] : feats[(size_t)(-2 - mm.w) * C_CH + c];
                ob[(size_t)c * PLANEQ] = v;
            }
        }
    }
}

// ---------- fallback path (if d_ws too small or M too large): zero + direct scatter ----------

__global__ void zero_out_kernel(float4* __restrict__ out, int nq) {
    int i = blockIdx.x * blockDim.x + threadIdx.x;
    if (i < nq) out[i] = make_float4(0.f, 0.f, 0.f, 0.f);
}

__global__ void scatter_feats_kernel(const float* __restrict__ feats,
                                     const int* __restrict__ bidx,
                                     const int* __restrict__ sidx,
                                     float* __restrict__ out, int M) {
    int tid = blockIdx.x * blockDim.x + threadIdx.x;
    if (tid >= M * C_CH) return;
    int m = tid >> 6;
    int c = tid & (C_CH - 1);
    int y = bidx[3 * m + 1];
    int x = bidx[3 * m + 2];
    int s = sidx[m];
    size_t o = (((size_t)s * C_CH + c) * NX + (NX - 1 - x)) * NY + y;
    out[o] = feats[tid];
}

extern "C" void kernel_launch(void* const* d_in, const int* in_sizes, int n_in,
                              void* d_out, int out_size, void* d_ws, size_t ws_size,
                              hipStream_t stream) {
    const float* feats = (const float*)d_in[0];
    const int*   bidx  = (const int*)d_in[1];
    const int*   sidx  = (const int*)d_in[2];
    float*       out   = (float*)d_out;

    const int M = in_sizes[0] / C_CH;               // 48000 pillars total
    const int B = out_size / (C_CH * NX * NY);      // 4

    const size_t map_elems = (size_t)B * NX * NY;   // 857,088
    const size_t map_bytes = map_elems * sizeof(unsigned short); // 1.7 MB
    const int nwg = B * NX;                         // 1728, divisible by 8

    if (ws_size >= map_bytes && (nwg % NXCD) == 0 && M < (int)EMPTY16) {
        unsigned short* map = (unsigned short*)d_ws;
        hipMemsetAsync(map, 0xFF, map_bytes, stream);   // all-0xFFFF sentinel
        scatter_idx_kernel<<<(M + 255) / 256, 256, 0, stream>>>(bidx, sidx, map, M);
        column_write_kernel<<<nwg, 256, 0, stream>>>(
            feats, map, (float4*)out, nwg);
    } else {
        int nq = out_size / 4;
        zero_out_kernel<<<(nq + 255) / 256, 256, 0, stream>>>((float4*)out, nq);
        int nt = M * C_CH;
        scatter_feats_kernel<<<(nt + 255) / 256, 256, 0, stream>>>(
            feats, bidx, sidx, out, M);
    }
}